// Round 15
// baseline (336.818 us; speedup 1.0000x reference)
//
#include <hip/hip_runtime.h>
#include <hip/hip_bf16.h>

// RGCN 2-layer + global mean pool + log_softmax. Round 15.
// R14 (333us) + kappa atomics moved OUT of build (they were ~50MB of random
// memory-level fp32 RMWs serializing build at 89us w/ VALUBusy 2%) and INTO
// rgcn1_fused's preamble: each wave handles a 256-edge slice, fire-and-forget
// atomics hidden in the latency-bound gather's idle memory slots.

#define CH 64
#define BK_EDGES 2048
#define CAP 12288   // per-bucket record capacity (avg ~8163, >40 sigma)

typedef __attribute__((ext_vector_type(8))) short short8;
typedef __attribute__((ext_vector_type(4))) float f32x4;

__device__ inline ushort f2bf(float f) {
    unsigned b = __float_as_uint(f);
    unsigned r = (b + 0x7FFFu + ((b >> 16) & 1u)) >> 16;
    return (ushort)r;
}
__device__ inline float bf2f(ushort u) {
    return __uint_as_float(((unsigned)u) << 16);
}

// ---- prep: bin (blocks [0,nBin)) + xbf (next nXbf) + wfrag (last) ----------

__global__ __launch_bounds__(256) void prep_kernel(
    const int* __restrict__ src, const int* __restrict__ dst,
    const int* __restrict__ etype, const float* __restrict__ x,
    const float* __restrict__ W1, const float* __restrict__ root1,
    int* __restrict__ gBucketCnt, int2* __restrict__ bucket_buf,
    ushort* __restrict__ xbf, ushort* __restrict__ wf,
    int E, int N, int nBin, int nXbf)
{
    __shared__ int s_k[BK_EDGES];
    __shared__ int s_y[BK_EDGES];
    __shared__ int hist[256], scanv[256], lcur[256], bstart[256], gbase[256];
    const int t = threadIdx.x;
    const int bid = blockIdx.x;

    if (bid >= nBin) {
        if (bid < nBin + nXbf) {          // bf16 copy of x
            int i = (bid - nBin) * 256 + t;
            if (i < N * CH / 4) {
                float4 v = ((const float4*)x)[i];
                ((ushort4*)xbf)[i] = make_ushort4(f2bf(v.x), f2bf(v.y), f2bf(v.z), f2bf(v.w));
            }
        } else {                          // weight B-fragment swizzle (9 mats)
            int idx = (bid - nBin - nXbf) * 256 + t;
            if (idx < 9 * 2 * 4 * 64 * 8) {
                int j    = idx & 7;
                int lane = (idx >> 3) & 63;
                int ct   = (idx >> 9) & 3;
                int ks   = (idx >> 11) & 1;
                int rel  = idx >> 12;
                int k = ks * 32 + (lane >> 4) * 8 + j;
                int n = ct * 16 + (lane & 15);
                float v = (rel < 8) ? W1[((size_t)rel * 64 + k) * 64 + n]
                                    : root1[(size_t)k * 64 + n];
                wf[idx] = f2bf(v);
            }
        }
        return;
    }

    // ---- bin: block-local counting sort by coarse bucket (key>>12) ----
    const int e0 = bid * BK_EDGES;
    const int cnt = min(BK_EDGES, E - e0);

    hist[t] = 0;
    __syncthreads();

    int myb[8], myk[8], myy[8];
    #pragma unroll
    for (int i = 0; i < 8; ++i) {
        int li = t + i * 256;
        if (li < cnt) {
            int e = e0 + li;
            int r = etype[e];
            int k = r * N + dst[e];
            myk[i] = k;
            myy[i] = (r << 17) | src[e];
            myb[i] = k >> 12;
            atomicAdd(&hist[myb[i]], 1);
        } else myb[i] = -1;
    }
    __syncthreads();

    int v = hist[t];
    scanv[t] = v;
    __syncthreads();
    for (int off = 1; off < 256; off <<= 1) {
        int u = (t >= off) ? scanv[t - off] : 0;
        __syncthreads();
        scanv[t] += u;
        __syncthreads();
    }
    int excl = scanv[t] - v;
    bstart[t] = excl;
    lcur[t] = excl;
    __syncthreads();

    #pragma unroll
    for (int i = 0; i < 8; ++i) {
        if (myb[i] >= 0) {
            int p = atomicAdd(&lcur[myb[i]], 1);
            s_k[p] = myk[i];
            s_y[p] = myy[i];
        }
    }
    __syncthreads();

    if (v > 0) gbase[t] = atomicAdd(&gBucketCnt[t], v);
    __syncthreads();

    for (int p = t; p < cnt; p += 256) {
        int k = s_k[p];
        int b = k >> 12;
        int gp = gbase[b] + (p - bstart[b]);
        if (gp < CAP)
            bucket_buf[(size_t)b * CAP + gp] = make_int2(k, s_y[p]);
    }
}

// ---- build: one WG (1024 threads) per bucket; self-computed base;
//      LDS hist + scan; coalesced rowptr/inv; LDS-cursor placement ----------

__global__ __launch_bounds__(1024) void build_kernel(
    const int2* __restrict__ bucket_buf, const int* __restrict__ gBucketCnt,
    int* __restrict__ rowptr, float* __restrict__ inv,
    int* __restrict__ perm, int N)
{
    __shared__ int hist[4096];
    __shared__ int cur[4096];
    __shared__ int part[1024];
    const int b = blockIdx.x;
    const int t = threadIdx.x;
    const int nb = min(gBucketCnt[b], CAP);
    const int2* rec = bucket_buf + (size_t)b * CAP;

    // bucket base = exclusive prefix of gBucketCnt (256 entries, zero-padded)
    int bc = (t < 256) ? gBucketCnt[t] : 0;
    part[t] = bc;
    __syncthreads();
    for (int off = 1; off < 1024; off <<= 1) {
        int u = (t >= off) ? part[t - off] : 0;
        __syncthreads();
        part[t] += u;
        __syncthreads();
    }
    __shared__ int baseS;
    if (t == b) baseS = part[t] - bc;
    __syncthreads();
    const int base = baseS;

    for (int i = t; i < 4096; i += 1024) hist[i] = 0;
    __syncthreads();
    for (int j = t; j < nb; j += 1024) atomicAdd(&hist[rec[j].x & 4095], 1);
    __syncthreads();

    const int i0 = t * 4;
    int h0 = hist[i0], h1 = hist[i0 + 1], h2 = hist[i0 + 2], h3 = hist[i0 + 3];
    int s = h0 + h1 + h2 + h3;
    part[t] = s;
    __syncthreads();
    for (int off = 1; off < 1024; off <<= 1) {
        int u = (t >= off) ? part[t - off] : 0;
        __syncthreads();
        part[t] += u;
        __syncthreads();
    }
    int run = base + part[t] - s;
    int hk[4] = {h0, h1, h2, h3};
    #pragma unroll
    for (int k = 0; k < 4; ++k) {
        cur[i0 + k] = run;
        rowptr[b * 4096 + i0 + k] = run;
        inv[b * 4096 + i0 + k] = 1.0f / (float)max(hk[k], 1);
        run += hk[k];
    }
    __syncthreads();

    for (int j = t; j < nb; j += 1024) {
        int k = rec[j].x, y = rec[j].y;
        int lk = k & 4095;
        int pos = atomicAdd(&cur[lk], 1);      // LDS cursor
        perm[pos] = y & 0x1FFFF;
    }
}

// ---- fused layer 1 (+ kappa preamble) ---------------------------------------
// Preamble: each wave fires kappa atomics for its 256-edge slice (hidden in
// the gather's idle memory slots; fire-and-forget, no result dependency).
// Then: one wave per 16-node tile, 2-chain depth-2 prefetch gather, bf16
// A-tile to LDS, 16x16x32 MFMA vs pre-swizzled W frags.

__global__ __launch_bounds__(256) void rgcn1_fused_kernel(
    const int* __restrict__ rowptr, const int* __restrict__ perm,
    const float* __restrict__ inv, const ushort* __restrict__ xbf,
    const ushort* __restrict__ wfrag, const float* __restrict__ b1,
    const int* __restrict__ srcE, const int* __restrict__ dstE,
    const int* __restrict__ etypeE, float* __restrict__ kappa,
    float* __restrict__ h, int N, int E, int nWaves)
{
    __shared__ ushort Abuf[4][16 * 72];   // 16x64 bf16 A-tile, row stride 72
    __shared__ int    rpS[4][144];        // rowptr[r*N+base+mm], i = r*17+mm
    __shared__ float  invS[4][128];       // inv[r*N+base+m],     i = r*16+m
    const int widx = threadIdx.x >> 6;
    const int lane = threadIdx.x & 63;
    const int wid = (blockIdx.x << 2) | widx;

    {   // kappa slice: fire-and-forget atomics for edges of this wave
        const int chunk = (E + nWaves - 1) / nWaves;
        const int eLo = wid * chunk;
        const int eHi = min(eLo + chunk, E);
        for (int e = eLo + lane; e < eHi; e += 64) {
            int r = etypeE[e];
            int d = dstE[e];
            int s = srcE[e];
            unsafeAtomicAdd(&kappa[(s << 3) | r], inv[(size_t)r * N + d]);
        }
    }

    const int base = wid << 4;
    if (base >= N) return;

    const int m0 = lane & 15;
    const int q  = lane >> 4;
    const int sg = lane >> 3;
    const int cg = lane & 7;
    ushort* ab = Abuf[widx];
    int*    rpL = rpS[widx];
    float*  ivL = invS[widx];

    for (int i = lane; i < 136; i += 64) {
        int r = i / 17, mm = i - r * 17;
        rpL[i] = rowptr[(size_t)r * N + base + mm];
    }
    for (int i = lane; i < 128; i += 64)
        ivL[i] = inv[(size_t)(i >> 4) * N + base + (i & 15)];

    f32x4 acc4[4];
    #pragma unroll
    for (int ct = 0; ct < 4; ++ct) acc4[ct] = (f32x4)(0.0f);

    for (int r = 0; r < 8; ++r) {
        const int iA = r * 17 + sg;
        const int iB = iA + 8;
        int jA = rpL[iA], eA = rpL[iA + 1];
        int jB = rpL[iB], eB = rpL[iB + 1];
        float a[8] = {}, bacc[8] = {};
        int s0A = perm[(jA     < eA) ? jA     : 0];
        int s1A = perm[(jA + 1 < eA) ? jA + 1 : 0];
        int s0B = perm[(jB     < eB) ? jB     : 0];
        int s1B = perm[(jB + 1 < eB) ? jB + 1 : 0];
        while (jA < eA || jB < eB) {
            short8 r0A = *(const short8*)&xbf[(size_t)s0A * CH + (cg << 3)];
            short8 r1A = *(const short8*)&xbf[(size_t)s1A * CH + (cg << 3)];
            short8 r0B = *(const short8*)&xbf[(size_t)s0B * CH + (cg << 3)];
            short8 r1B = *(const short8*)&xbf[(size_t)s1B * CH + (cg << 3)];
            int t0A = perm[(jA + 2 < eA) ? jA + 2 : 0];   // prefetch next pair
            int t1A = perm[(jA + 3 < eA) ? jA + 3 : 0];
            int t0B = perm[(jB + 2 < eB) ? jB + 2 : 0];
            int t1B = perm[(jB + 3 < eB) ? jB + 3 : 0];
            float m0A = (jA     < eA) ? 1.f : 0.f;
            float m1A = (jA + 1 < eA) ? 1.f : 0.f;
            float m0B = (jB     < eB) ? 1.f : 0.f;
            float m1B = (jB + 1 < eB) ? 1.f : 0.f;
            #pragma unroll
            for (int k = 0; k < 8; ++k) {
                a[k]    += m0A * bf2f((ushort)r0A[k]) + m1A * bf2f((ushort)r1A[k]);
                bacc[k] += m0B * bf2f((ushort)r0B[k]) + m1B * bf2f((ushort)r1B[k]);
            }
            s0A = t0A; s1A = t1A; s0B = t0B; s1B = t1B;
            jA += 2; jB += 2;
        }
        const float ivA = ivL[(r << 4) | sg];
        const float ivB = ivL[(r << 4) | (8 + sg)];
        short8 oA, oB;
        #pragma unroll
        for (int k = 0; k < 8; ++k) {
            oA[k] = (short)f2bf(a[k] * ivA);
            oB[k] = (short)f2bf(bacc[k] * ivB);
        }
        *(short8*)&ab[sg * 72 + (cg << 3)]       = oA;
        *(short8*)&ab[(8 + sg) * 72 + (cg << 3)] = oB;

        // MFMA: 2 K-steps x 4 col-tiles (per-wave LDS is program-ordered)
        #pragma unroll
        for (int s = 0; s < 2; ++s) {
            short8 av = *(short8*)&ab[m0 * 72 + s * 32 + q * 8];
            #pragma unroll
            for (int ct = 0; ct < 4; ++ct) {
                short8 bv = *(const short8*)&wfrag[(((size_t)(r * 2 + s) * 4 + ct) * 64 + lane) * 8];
                acc4[ct] = __builtin_amdgcn_mfma_f32_16x16x32_bf16(av, bv, acc4[ct], 0, 0, 0);
            }
        }
    }

    {   // root: A-frag = x rows directly (rel index 8 in wfrag)
        int node = min(base + m0, N - 1);
        #pragma unroll
        for (int s = 0; s < 2; ++s) {
            short8 av = *(const short8*)&xbf[(size_t)node * CH + s * 32 + q * 8];
            #pragma unroll
            for (int ct = 0; ct < 4; ++ct) {
                short8 bv = *(const short8*)&wfrag[(((size_t)(8 * 2 + s) * 4 + ct) * 64 + lane) * 8];
                acc4[ct] = __builtin_amdgcn_mfma_f32_16x16x32_bf16(av, bv, acc4[ct], 0, 0, 0);
            }
        }
    }

    // epilogue: D[row=q*4+v][col=ct*16+m0]
    #pragma unroll
    for (int ct = 0; ct < 4; ++ct) {
        int c = ct * 16 + m0;
        float bb = b1[c];
        #pragma unroll
        for (int v = 0; v < 4; ++v) {
            int node = base + q * 4 + v;
            if (node < N)
                h[(size_t)node * CH + c] = fmaxf(acc4[ct][v] + bb, 0.f);
        }
    }
}

// ---- layer-2 collapse -------------------------------------------------------

__global__ __launch_bounds__(256) void kred_kernel(
    const float* __restrict__ h, const float* __restrict__ kappa,
    float* __restrict__ sacc, int N)
{
    const int lane = threadIdx.x & 63;
    const int w = threadIdx.x >> 6;
    int wave = (blockIdx.x << 2) | w;
    const int wstride = gridDim.x << 2;
    float racc[9] = {};
    for (int i = wave; i < N; i += wstride) {
        float hv = h[(size_t)i * CH + lane];
        #pragma unroll
        for (int r = 0; r < 8; ++r) racc[r] += hv * kappa[i * 8 + r];
        racc[8] += hv;
    }
    __shared__ float red[4][9][64];
    #pragma unroll
    for (int r = 0; r < 9; ++r) red[w][r][lane] = racc[r];
    __syncthreads();
    if (w == 0) {
        #pragma unroll
        for (int r = 0; r < 9; ++r) {
            float s4 = red[0][r][lane] + red[1][r][lane] + red[2][r][lane] + red[3][r][lane];
            unsafeAtomicAdd(&sacc[r * 64 + lane], s4);
        }
    }
}

__global__ void finalize_kernel(const float* __restrict__ sacc, const float* __restrict__ root2,
                                const float* __restrict__ W2, const float* __restrict__ b2,
                                float* __restrict__ out, float invN)
{
    __shared__ float g[16];
    int t = threadIdx.x;
    if (t < 16) {
        const float* s0 = sacc + 512;
        float acc = 0.f;
        for (int c = 0; c < 64; ++c) acc += s0[c] * root2[c * 16 + t];
        for (int r = 0; r < 8; ++r) {
            const float* sr = sacc + r * 64;
            for (int c = 0; c < 64; ++c) acc += sr[c] * W2[(r * 64 + c) * 16 + t];
        }
        g[t] = acc * invN + b2[t];
    }
    __syncthreads();
    if (t < 16) {
        float m = -1e30f;
        for (int i = 0; i < 16; ++i) m = fmaxf(m, g[i]);
        float s = 0.f;
        for (int i = 0; i < 16; ++i) s += expf(g[i] - m);
        out[t] = g[t] - (m + logf(s));
    }
}

// ---- launch -----------------------------------------------------------------

extern "C" void kernel_launch(void* const* d_in, const int* in_sizes, int n_in,
                              void* d_out, int out_size, void* d_ws, size_t ws_size,
                              hipStream_t stream)
{
    const float* x     = (const float*)d_in[0];
    const int*   eidx  = (const int*)d_in[1];
    const int*   etype = (const int*)d_in[2];
    const float* W1    = (const float*)d_in[3];
    const float* root1 = (const float*)d_in[4];
    const float* b1    = (const float*)d_in[5];
    const float* W2    = (const float*)d_in[6];
    const float* root2 = (const float*)d_in[7];
    const float* b2    = (const float*)d_in[8];
    float* out = (float*)d_out;

    const int E = in_sizes[1] / 2;
    const int N = in_sizes[0] / CH;
    const int NKEY = N * 8;
    const int NBUK = (NKEY + 4095) / 4096;         // 196 for N=100K (<=256)
    const int KSPACE = NBUK << 12;
    const int* srcI = eidx;
    const int* dstI = eidx + E;

    // workspace layout (4B units):
    // [gBucketCnt 256 | sacc 576 | kappa NKEY]   <- zeroed prefix
    // [inv KSPACE | rowptr KSPACE+16 | perm E | bucket_buf (8B-al) NBUK*CAP*2 |
    //  xbf N*CH/2 | wfrag 18432 | h N*CH]
    int* wsi = (int*)d_ws;
    int*   gBucketCnt = wsi;
    float* sacc       = (float*)(gBucketCnt + 256);
    float* kappa      = sacc + 576;
    float* inv        = kappa + NKEY;
    int*   rowptr     = (int*)(inv + KSPACE);
    int*   perm       = rowptr + KSPACE + 16;
    size_t off = (size_t)((perm + E) - wsi);
    off = (off + 1) & ~(size_t)1;                  // 8B-align
    int2*  bucket_buf = (int2*)(wsi + off);
    off += (size_t)NBUK * CAP * 2;
    off = (off + 7) & ~(size_t)7;                  // 32B-align
    ushort* xbf = (ushort*)(wsi + off);
    ushort* wfg = xbf + (size_t)N * CH;
    float*  h   = (float*)(wfg + 36864);

    hipMemsetAsync(d_ws, 0, (size_t)(256 + 576 + NKEY) * 4, stream);

    const int nBin = (E + BK_EDGES - 1) / BK_EDGES;
    const int nXbf = (N * CH / 4 + 255) / 256;
    const int nWf  = (36864 + 255) / 256;
    prep_kernel<<<nBin + nXbf + nWf, 256, 0, stream>>>(
        srcI, dstI, etype, x, W1, root1, gBucketCnt, bucket_buf, xbf, wfg,
        E, N, nBin, nXbf);

    build_kernel<<<NBUK, 1024, 0, stream>>>(
        bucket_buf, gBucketCnt, rowptr, inv, perm, N);

    const int tiles = (N + 15) / 16;
    rgcn1_fused_kernel<<<(tiles + 3) / 4, 256, 0, stream>>>(
        rowptr, perm, inv, xbf, wfg, b1, srcI, dstI, etype, kappa, h, N, E, tiles);

    kred_kernel<<<1024, 256, 0, stream>>>(h, kappa, sacc, N);
    finalize_kernel<<<1, 64, 0, stream>>>(sacc, root2, W2, b2, out, 1.0f / (float)N);
}

// Round 16
// 309.785 us; speedup vs baseline: 1.0873x; 1.0873x over previous
//
#include <hip/hip_runtime.h>
#include <hip/hip_bf16.h>

// RGCN 2-layer + global mean pool + log_softmax. Round 16.
// R15 lesson: kappa atomics in the gather waves' preamble serialize via
// ordered vmcnt (atomics ahead of loads in queue -> every gather waitcnt
// drains them). Fix: 128 DEDICATED kappa blocks at the head of the fused
// grid -- atomic-only waves with no dependent loads, co-resident with
// gather waves, soaking spare BW. Gather path carries zero atomic code.
// Build stays kappa-free (R15). Everything else = R14/R13 proven code.

#define CH 64
#define BK_EDGES 2048
#define CAP 12288   // per-bucket record capacity (avg ~8163, >40 sigma)
#define KB 128      // dedicated kappa blocks at head of fused grid

typedef __attribute__((ext_vector_type(8))) short short8;
typedef __attribute__((ext_vector_type(4))) float f32x4;

__device__ inline ushort f2bf(float f) {
    unsigned b = __float_as_uint(f);
    unsigned r = (b + 0x7FFFu + ((b >> 16) & 1u)) >> 16;
    return (ushort)r;
}
__device__ inline float bf2f(ushort u) {
    return __uint_as_float(((unsigned)u) << 16);
}

// ---- prep: bin (blocks [0,nBin)) + xbf (next nXbf) + wfrag (last) ----------

__global__ __launch_bounds__(256) void prep_kernel(
    const int* __restrict__ src, const int* __restrict__ dst,
    const int* __restrict__ etype, const float* __restrict__ x,
    const float* __restrict__ W1, const float* __restrict__ root1,
    int* __restrict__ gBucketCnt, int2* __restrict__ bucket_buf,
    ushort* __restrict__ xbf, ushort* __restrict__ wf,
    int E, int N, int nBin, int nXbf)
{
    __shared__ int s_k[BK_EDGES];
    __shared__ int s_y[BK_EDGES];
    __shared__ int hist[256], scanv[256], lcur[256], bstart[256], gbase[256];
    const int t = threadIdx.x;
    const int bid = blockIdx.x;

    if (bid >= nBin) {
        if (bid < nBin + nXbf) {          // bf16 copy of x
            int i = (bid - nBin) * 256 + t;
            if (i < N * CH / 4) {
                float4 v = ((const float4*)x)[i];
                ((ushort4*)xbf)[i] = make_ushort4(f2bf(v.x), f2bf(v.y), f2bf(v.z), f2bf(v.w));
            }
        } else {                          // weight B-fragment swizzle (9 mats)
            int idx = (bid - nBin - nXbf) * 256 + t;
            if (idx < 9 * 2 * 4 * 64 * 8) {
                int j    = idx & 7;
                int lane = (idx >> 3) & 63;
                int ct   = (idx >> 9) & 3;
                int ks   = (idx >> 11) & 1;
                int rel  = idx >> 12;
                int k = ks * 32 + (lane >> 4) * 8 + j;
                int n = ct * 16 + (lane & 15);
                float v = (rel < 8) ? W1[((size_t)rel * 64 + k) * 64 + n]
                                    : root1[(size_t)k * 64 + n];
                wf[idx] = f2bf(v);
            }
        }
        return;
    }

    // ---- bin: block-local counting sort by coarse bucket (key>>12) ----
    const int e0 = bid * BK_EDGES;
    const int cnt = min(BK_EDGES, E - e0);

    hist[t] = 0;
    __syncthreads();

    int myb[8], myk[8], myy[8];
    #pragma unroll
    for (int i = 0; i < 8; ++i) {
        int li = t + i * 256;
        if (li < cnt) {
            int e = e0 + li;
            int r = etype[e];
            int k = r * N + dst[e];
            myk[i] = k;
            myy[i] = (r << 17) | src[e];
            myb[i] = k >> 12;
            atomicAdd(&hist[myb[i]], 1);
        } else myb[i] = -1;
    }
    __syncthreads();

    int v = hist[t];
    scanv[t] = v;
    __syncthreads();
    for (int off = 1; off < 256; off <<= 1) {
        int u = (t >= off) ? scanv[t - off] : 0;
        __syncthreads();
        scanv[t] += u;
        __syncthreads();
    }
    int excl = scanv[t] - v;
    bstart[t] = excl;
    lcur[t] = excl;
    __syncthreads();

    #pragma unroll
    for (int i = 0; i < 8; ++i) {
        if (myb[i] >= 0) {
            int p = atomicAdd(&lcur[myb[i]], 1);
            s_k[p] = myk[i];
            s_y[p] = myy[i];
        }
    }
    __syncthreads();

    if (v > 0) gbase[t] = atomicAdd(&gBucketCnt[t], v);
    __syncthreads();

    for (int p = t; p < cnt; p += 256) {
        int k = s_k[p];
        int b = k >> 12;
        int gp = gbase[b] + (p - bstart[b]);
        if (gp < CAP)
            bucket_buf[(size_t)b * CAP + gp] = make_int2(k, s_y[p]);
    }
}

// ---- build: one WG (1024 threads) per bucket; self-computed base;
//      LDS hist + scan; coalesced rowptr/inv; LDS-cursor placement ----------

__global__ __launch_bounds__(1024) void build_kernel(
    const int2* __restrict__ bucket_buf, const int* __restrict__ gBucketCnt,
    int* __restrict__ rowptr, float* __restrict__ inv,
    int* __restrict__ perm, int N)
{
    __shared__ int hist[4096];
    __shared__ int cur[4096];
    __shared__ int part[1024];
    const int b = blockIdx.x;
    const int t = threadIdx.x;
    const int nb = min(gBucketCnt[b], CAP);
    const int2* rec = bucket_buf + (size_t)b * CAP;

    // bucket base = exclusive prefix of gBucketCnt (256 entries, zero-padded)
    int bc = (t < 256) ? gBucketCnt[t] : 0;
    part[t] = bc;
    __syncthreads();
    for (int off = 1; off < 1024; off <<= 1) {
        int u = (t >= off) ? part[t - off] : 0;
        __syncthreads();
        part[t] += u;
        __syncthreads();
    }
    __shared__ int baseS;
    if (t == b) baseS = part[t] - bc;
    __syncthreads();
    const int base = baseS;

    for (int i = t; i < 4096; i += 1024) hist[i] = 0;
    __syncthreads();
    for (int j = t; j < nb; j += 1024) atomicAdd(&hist[rec[j].x & 4095], 1);
    __syncthreads();

    const int i0 = t * 4;
    int h0 = hist[i0], h1 = hist[i0 + 1], h2 = hist[i0 + 2], h3 = hist[i0 + 3];
    int s = h0 + h1 + h2 + h3;
    part[t] = s;
    __syncthreads();
    for (int off = 1; off < 1024; off <<= 1) {
        int u = (t >= off) ? part[t - off] : 0;
        __syncthreads();
        part[t] += u;
        __syncthreads();
    }
    int run = base + part[t] - s;
    int hk[4] = {h0, h1, h2, h3};
    #pragma unroll
    for (int k = 0; k < 4; ++k) {
        cur[i0 + k] = run;
        rowptr[b * 4096 + i0 + k] = run;
        inv[b * 4096 + i0 + k] = 1.0f / (float)max(hk[k], 1);
        run += hk[k];
    }
    __syncthreads();

    for (int j = t; j < nb; j += 1024) {
        int k = rec[j].x, y = rec[j].y;
        int lk = k & 4095;
        int pos = atomicAdd(&cur[lk], 1);      // LDS cursor
        perm[pos] = y & 0x1FFFF;
    }
}

// ---- fused layer 1 + dedicated kappa blocks --------------------------------
// blocks [0,KB): atomic-only kappa waves (no dependent loads -> no vmcnt
// coupling; drain by kernel end). blocks [KB,..): one wave per 16-node tile,
// 2-chain depth-2 prefetch gather, bf16 A-tile to LDS, 16x16x32 MFMA.

__global__ __launch_bounds__(256) void rgcn1_fused_kernel(
    const int* __restrict__ rowptr, const int* __restrict__ perm,
    const float* __restrict__ inv, const ushort* __restrict__ xbf,
    const ushort* __restrict__ wfrag, const float* __restrict__ b1,
    const int* __restrict__ srcE, const int* __restrict__ dstE,
    const int* __restrict__ etypeE, float* __restrict__ kappa,
    float* __restrict__ h, int N, int E)
{
    if (blockIdx.x < KB) {
        // kappa-only block: slice of edges, fire-and-forget atomics
        const int chunk = (E + KB - 1) / KB;
        const int lo = blockIdx.x * chunk;
        const int hi = min(lo + chunk, E);
        for (int e = lo + (int)threadIdx.x; e < hi; e += 256) {
            int r = etypeE[e];
            int d = dstE[e];
            int s = srcE[e];
            unsafeAtomicAdd(&kappa[(s << 3) | r], inv[(size_t)r * N + d]);
        }
        return;
    }

    __shared__ ushort Abuf[4][16 * 72];   // 16x64 bf16 A-tile, row stride 72
    __shared__ int    rpS[4][144];        // rowptr[r*N+base+mm], i = r*17+mm
    __shared__ float  invS[4][128];       // inv[r*N+base+m],     i = r*16+m
    const int widx = threadIdx.x >> 6;
    const int lane = threadIdx.x & 63;
    const int wid = ((blockIdx.x - KB) << 2) | widx;
    const int base = wid << 4;
    if (base >= N) return;

    const int m0 = lane & 15;
    const int q  = lane >> 4;
    const int sg = lane >> 3;
    const int cg = lane & 7;
    ushort* ab = Abuf[widx];
    int*    rpL = rpS[widx];
    float*  ivL = invS[widx];

    for (int i = lane; i < 136; i += 64) {
        int r = i / 17, mm = i - r * 17;
        rpL[i] = rowptr[(size_t)r * N + base + mm];
    }
    for (int i = lane; i < 128; i += 64)
        ivL[i] = inv[(size_t)(i >> 4) * N + base + (i & 15)];

    f32x4 acc4[4];
    #pragma unroll
    for (int ct = 0; ct < 4; ++ct) acc4[ct] = (f32x4)(0.0f);

    for (int r = 0; r < 8; ++r) {
        const int iA = r * 17 + sg;
        const int iB = iA + 8;
        int jA = rpL[iA], eA = rpL[iA + 1];
        int jB = rpL[iB], eB = rpL[iB + 1];
        float a[8] = {}, bacc[8] = {};
        int s0A = perm[(jA     < eA) ? jA     : 0];
        int s1A = perm[(jA + 1 < eA) ? jA + 1 : 0];
        int s0B = perm[(jB     < eB) ? jB     : 0];
        int s1B = perm[(jB + 1 < eB) ? jB + 1 : 0];
        while (jA < eA || jB < eB) {
            short8 r0A = *(const short8*)&xbf[(size_t)s0A * CH + (cg << 3)];
            short8 r1A = *(const short8*)&xbf[(size_t)s1A * CH + (cg << 3)];
            short8 r0B = *(const short8*)&xbf[(size_t)s0B * CH + (cg << 3)];
            short8 r1B = *(const short8*)&xbf[(size_t)s1B * CH + (cg << 3)];
            int t0A = perm[(jA + 2 < eA) ? jA + 2 : 0];   // prefetch next pair
            int t1A = perm[(jA + 3 < eA) ? jA + 3 : 0];
            int t0B = perm[(jB + 2 < eB) ? jB + 2 : 0];
            int t1B = perm[(jB + 3 < eB) ? jB + 3 : 0];
            float m0A = (jA     < eA) ? 1.f : 0.f;
            float m1A = (jA + 1 < eA) ? 1.f : 0.f;
            float m0B = (jB     < eB) ? 1.f : 0.f;
            float m1B = (jB + 1 < eB) ? 1.f : 0.f;
            #pragma unroll
            for (int k = 0; k < 8; ++k) {
                a[k]    += m0A * bf2f((ushort)r0A[k]) + m1A * bf2f((ushort)r1A[k]);
                bacc[k] += m0B * bf2f((ushort)r0B[k]) + m1B * bf2f((ushort)r1B[k]);
            }
            s0A = t0A; s1A = t1A; s0B = t0B; s1B = t1B;
            jA += 2; jB += 2;
        }
        const float ivA = ivL[(r << 4) | sg];
        const float ivB = ivL[(r << 4) | (8 + sg)];
        short8 oA, oB;
        #pragma unroll
        for (int k = 0; k < 8; ++k) {
            oA[k] = (short)f2bf(a[k] * ivA);
            oB[k] = (short)f2bf(bacc[k] * ivB);
        }
        *(short8*)&ab[sg * 72 + (cg << 3)]       = oA;
        *(short8*)&ab[(8 + sg) * 72 + (cg << 3)] = oB;

        // MFMA: 2 K-steps x 4 col-tiles (per-wave LDS is program-ordered)
        #pragma unroll
        for (int s = 0; s < 2; ++s) {
            short8 av = *(short8*)&ab[m0 * 72 + s * 32 + q * 8];
            #pragma unroll
            for (int ct = 0; ct < 4; ++ct) {
                short8 bv = *(const short8*)&wfrag[(((size_t)(r * 2 + s) * 4 + ct) * 64 + lane) * 8];
                acc4[ct] = __builtin_amdgcn_mfma_f32_16x16x32_bf16(av, bv, acc4[ct], 0, 0, 0);
            }
        }
    }

    {   // root: A-frag = x rows directly (rel index 8 in wfrag)
        int node = min(base + m0, N - 1);
        #pragma unroll
        for (int s = 0; s < 2; ++s) {
            short8 av = *(const short8*)&xbf[(size_t)node * CH + s * 32 + q * 8];
            #pragma unroll
            for (int ct = 0; ct < 4; ++ct) {
                short8 bv = *(const short8*)&wfrag[(((size_t)(8 * 2 + s) * 4 + ct) * 64 + lane) * 8];
                acc4[ct] = __builtin_amdgcn_mfma_f32_16x16x32_bf16(av, bv, acc4[ct], 0, 0, 0);
            }
        }
    }

    // epilogue: D[row=q*4+v][col=ct*16+m0]
    #pragma unroll
    for (int ct = 0; ct < 4; ++ct) {
        int c = ct * 16 + m0;
        float bb = b1[c];
        #pragma unroll
        for (int v = 0; v < 4; ++v) {
            int node = base + q * 4 + v;
            if (node < N)
                h[(size_t)node * CH + c] = fmaxf(acc4[ct][v] + bb, 0.f);
        }
    }
}

// ---- layer-2 collapse -------------------------------------------------------

__global__ __launch_bounds__(256) void kred_kernel(
    const float* __restrict__ h, const float* __restrict__ kappa,
    float* __restrict__ sacc, int N)
{
    const int lane = threadIdx.x & 63;
    const int w = threadIdx.x >> 6;
    int wave = (blockIdx.x << 2) | w;
    const int wstride = gridDim.x << 2;
    float racc[9] = {};
    for (int i = wave; i < N; i += wstride) {
        float hv = h[(size_t)i * CH + lane];
        #pragma unroll
        for (int r = 0; r < 8; ++r) racc[r] += hv * kappa[i * 8 + r];
        racc[8] += hv;
    }
    __shared__ float red[4][9][64];
    #pragma unroll
    for (int r = 0; r < 9; ++r) red[w][r][lane] = racc[r];
    __syncthreads();
    if (w == 0) {
        #pragma unroll
        for (int r = 0; r < 9; ++r) {
            float s4 = red[0][r][lane] + red[1][r][lane] + red[2][r][lane] + red[3][r][lane];
            unsafeAtomicAdd(&sacc[r * 64 + lane], s4);
        }
    }
}

__global__ void finalize_kernel(const float* __restrict__ sacc, const float* __restrict__ root2,
                                const float* __restrict__ W2, const float* __restrict__ b2,
                                float* __restrict__ out, float invN)
{
    __shared__ float g[16];
    int t = threadIdx.x;
    if (t < 16) {
        const float* s0 = sacc + 512;
        float acc = 0.f;
        for (int c = 0; c < 64; ++c) acc += s0[c] * root2[c * 16 + t];
        for (int r = 0; r < 8; ++r) {
            const float* sr = sacc + r * 64;
            for (int c = 0; c < 64; ++c) acc += sr[c] * W2[(r * 64 + c) * 16 + t];
        }
        g[t] = acc * invN + b2[t];
    }
    __syncthreads();
    if (t < 16) {
        float m = -1e30f;
        for (int i = 0; i < 16; ++i) m = fmaxf(m, g[i]);
        float s = 0.f;
        for (int i = 0; i < 16; ++i) s += expf(g[i] - m);
        out[t] = g[t] - (m + logf(s));
    }
}

// ---- launch -----------------------------------------------------------------

extern "C" void kernel_launch(void* const* d_in, const int* in_sizes, int n_in,
                              void* d_out, int out_size, void* d_ws, size_t ws_size,
                              hipStream_t stream)
{
    const float* x     = (const float*)d_in[0];
    const int*   eidx  = (const int*)d_in[1];
    const int*   etype = (const int*)d_in[2];
    const float* W1    = (const float*)d_in[3];
    const float* root1 = (const float*)d_in[4];
    const float* b1    = (const float*)d_in[5];
    const float* W2    = (const float*)d_in[6];
    const float* root2 = (const float*)d_in[7];
    const float* b2    = (const float*)d_in[8];
    float* out = (float*)d_out;

    const int E = in_sizes[1] / 2;
    const int N = in_sizes[0] / CH;
    const int NKEY = N * 8;
    const int NBUK = (NKEY + 4095) / 4096;         // 196 for N=100K (<=256)
    const int KSPACE = NBUK << 12;
    const int* srcI = eidx;
    const int* dstI = eidx + E;

    // workspace layout (4B units):
    // [gBucketCnt 256 | sacc 576 | kappa NKEY]   <- zeroed prefix
    // [inv KSPACE | rowptr KSPACE+16 | perm E | bucket_buf (8B-al) NBUK*CAP*2 |
    //  xbf N*CH/2 | wfrag 18432 | h N*CH]
    int* wsi = (int*)d_ws;
    int*   gBucketCnt = wsi;
    float* sacc       = (float*)(gBucketCnt + 256);
    float* kappa      = sacc + 576;
    float* inv        = kappa + NKEY;
    int*   rowptr     = (int*)(inv + KSPACE);
    int*   perm       = rowptr + KSPACE + 16;
    size_t off = (size_t)((perm + E) - wsi);
    off = (off + 1) & ~(size_t)1;                  // 8B-align
    int2*  bucket_buf = (int2*)(wsi + off);
    off += (size_t)NBUK * CAP * 2;
    off = (off + 7) & ~(size_t)7;                  // 32B-align
    ushort* xbf = (ushort*)(wsi + off);
    ushort* wfg = xbf + (size_t)N * CH;
    float*  h   = (float*)(wfg + 36864);

    hipMemsetAsync(d_ws, 0, (size_t)(256 + 576 + NKEY) * 4, stream);

    const int nBin = (E + BK_EDGES - 1) / BK_EDGES;
    const int nXbf = (N * CH / 4 + 255) / 256;
    const int nWf  = (36864 + 255) / 256;
    prep_kernel<<<nBin + nXbf + nWf, 256, 0, stream>>>(
        srcI, dstI, etype, x, W1, root1, gBucketCnt, bucket_buf, xbf, wfg,
        E, N, nBin, nXbf);

    build_kernel<<<NBUK, 1024, 0, stream>>>(
        bucket_buf, gBucketCnt, rowptr, inv, perm, N);

    const int tiles = (N + 15) / 16;
    rgcn1_fused_kernel<<<KB + (tiles + 3) / 4, 256, 0, stream>>>(
        rowptr, perm, inv, xbf, wfg, b1, srcI, dstI, etype, kappa, h, N, E);

    kred_kernel<<<1024, 256, 0, stream>>>(h, kappa, sacc, N);
    finalize_kernel<<<1, 64, 0, stream>>>(sacc, root2, W2, b2, out, 1.0f / (float)N);
}